// Round 1
// baseline (554.432 us; speedup 1.0000x reference)
//
#include <hip/hip_runtime.h>
#include <stdint.h>

typedef unsigned short u16;
typedef __bf16 bf16x8 __attribute__((ext_vector_type(8)));
typedef float  f32x16 __attribute__((ext_vector_type(16)));
typedef short  short8v __attribute__((ext_vector_type(8)));

#define COEF_S 0.044194173824159216f   // 1/sqrt(512)
#define COEF_W 0.014731391274719738f   // 1/sqrt(4608)

static __device__ __forceinline__ bf16x8 as_b(short8v v) {
  union { short8v s; bf16x8 b; } u; u.s = v; return u.b;
}

// s[n][c] = dlatent[n] @ (mod_weight*COEF_S) + mod_bias + 1
__global__ void style_k(const float* __restrict__ dl, const float* __restrict__ mw,
                        const float* __restrict__ mb, float* __restrict__ s) {
  int idx = blockIdx.x * 256 + threadIdx.x;      // 0..4095
  int n = idx >> 9, c = idx & 511;
  const float* dln = dl + n * 512;
  float acc = 0.f;
  for (int l = 0; l < 512; ++l) acc = fmaf(dln[l], mw[l * 512 + c], acc);
  s[idx] = acc * COEF_S + mb[c] + 1.0f;
}

// wsq[cin][f] = COEF_W^2 * sum_tap w[tap][cin][f]^2
__global__ void wsq_k(const float* __restrict__ w, float* __restrict__ wsq) {
  int idx = blockIdx.x * 256 + threadIdx.x;      // 0..262143  (cin*512+f)
  float acc = 0.f;
#pragma unroll
  for (int t = 0; t < 9; ++t) { float v = w[t * 262144 + idx]; acc = fmaf(v, v, acc); }
  wsq[idx] = acc * (1.0f / 4608.0f);
}

// d[n][f] = rsqrt( sum_c s[n][c]^2 * wsq[c][f] + 1e-8 )
__global__ void dcoef_k(const float* __restrict__ s, const float* __restrict__ wsq,
                        float* __restrict__ d) {
  int idx = blockIdx.x * 256 + threadIdx.x;      // 0..4095
  int n = idx >> 9, f = idx & 511;
  const float* sn = s + n * 512;
  float acc = 0.f;
  for (int c = 0; c < 512; ++c) { float sv = sn[c]; acc = fmaf(sv * sv, wsq[c * 512 + f], acc); }
  d[idx] = 1.0f / sqrtf(acc + 1e-8f);
}

// wT_hi/lo[tap][f][cin] (bf16 split of w*COEF_W), transposed via LDS
__global__ void wsplit_k(const float* __restrict__ w, u16* __restrict__ whi,
                         u16* __restrict__ wlo) {
  __shared__ float T[64 * 68];
  int bid = blockIdx.x;                 // 0..575
  int tap = bid >> 6, r = bid & 63;
  int f0 = (r >> 3) * 64, c0 = (r & 7) * 64;
  int t = threadIdx.x;
#pragma unroll
  for (int rep = 0; rep < 4; ++rep) {
    int slot = rep * 256 + t;           // 0..1023
    int cl = slot >> 4, fq = slot & 15;
    float4 v = *(const float4*)(w + (tap * 512 + c0 + cl) * 512 + f0 + 4 * fq);
    v.x *= COEF_W; v.y *= COEF_W; v.z *= COEF_W; v.w *= COEF_W;
    *(float4*)(T + cl * 68 + 4 * fq) = v;
  }
  __syncthreads();
#pragma unroll
  for (int rep = 0; rep < 16; ++rep) {
    int slot = rep * 256 + t;           // 0..4095
    int fl = slot >> 6, cl = slot & 63;
    float v = T[cl * 68 + fl];
    unsigned b = __float_as_uint(v);
    u16 hi = (u16)(b >> 16);
    float rem = v - __uint_as_float(b & 0xffff0000u);
    u16 lo = (u16)(__float_as_uint(rem) >> 16);
    int oidx = (tap * 512 + f0 + fl) * 512 + c0 + cl;
    whi[oidx] = hi;
    wlo[oidx] = lo;
  }
}

// Main conv: C[f 128][px 256] per block; px tile = 4 rows of 64.
// K-loop: cin chunks of 32, inner 9 taps; split-bf16 3-MFMA per logical f32 MFMA.
#define CPAD 40
__launch_bounds__(256, 2)
__global__ void conv_k(const float* __restrict__ x, const float* __restrict__ s,
                       const float* __restrict__ dco,
                       const u16* __restrict__ whi, const u16* __restrict__ wlo,
                       float* __restrict__ out) {
  __shared__ u16 Xh[6 * 66 * CPAD];
  __shared__ u16 Xl[6 * 66 * CPAD];

  int bid = blockIdx.x;            // 0..511
  int n = bid >> 6;
  int r = bid & 63;
  int ft = r >> 4;                 // 0..3  (f tile of 128)
  int rt = r & 15;                 // 0..15 (row tile of 4)
  int h0 = rt * 4;
  int tid = threadIdx.x;
  int lane = tid & 63;
  int wav = tid >> 6;
  int wm = wav >> 1, wn = wav & 1;
  int fw = ft * 128 + wm * 64;     // wave f base
  int pxw = wn * 128;              // wave px base
  int li = lane & 31;
  int lq = lane >> 5;              // 0/1

  f32x16 acc[2][4];
#pragma unroll
  for (int a = 0; a < 2; ++a)
#pragma unroll
    for (int b = 0; b < 4; ++b)
#pragma unroll
      for (int e = 0; e < 16; ++e) acc[a][b][e] = 0.0f;

  // zero the SAME-padding columns (scol 0 and 65) once
  for (int slot = tid; slot < 384; slot += 256) {
    int sr = slot >> 6; int e = (slot >> 5) & 1; int cc = slot & 31;
    int off = (sr * 66 + (e ? 65 : 0)) * CPAD + cc;
    Xh[off] = 0; Xl[off] = 0;
  }

  const float* xn = x + n * 512 * 64 * 64;
  const float* sn = s + n * 512;

  for (int c0 = 0; c0 < 512; c0 += 32) {
    __syncthreads();   // also covers the pad-zero fill on first iteration
    // ---- stage x*s into LDS as bf16 hi/lo, layout [sr 6][scol 66][cin CPAD]
#pragma unroll
    for (int rep = 0; rep < 12; ++rep) {
      int slot = rep * 256 + tid;        // 0..3071
      int row = slot >> 4;               // 0..191
      int q = slot & 15;                 // 16 float4 per row
      int cc = row & 31, sr = row >> 5;  // sr 0..5
      int h = h0 - 1 + sr;
      float sv = sn[c0 + cc];
      float4 v = make_float4(0.f, 0.f, 0.f, 0.f);
      if (h >= 0 && h < 64) v = *(const float4*)(xn + ((c0 + cc) * 64 + h) * 64 + 4 * q);
      float vv[4] = {v.x * sv, v.y * sv, v.z * sv, v.w * sv};
      int ob = (sr * 66 + 1 + 4 * q) * CPAD + cc;
#pragma unroll
      for (int j = 0; j < 4; ++j) {
        unsigned b = __float_as_uint(vv[j]);
        u16 hi = (u16)(b >> 16);
        float rem = vv[j] - __uint_as_float(b & 0xffff0000u);
        u16 lo = (u16)(__float_as_uint(rem) >> 16);
        Xh[ob + j * CPAD] = hi;
        Xl[ob + j * CPAD] = lo;
      }
    }
    __syncthreads();
    // ---- compute: 9 taps x 2 k-steps of 32x32x16 MFMA
    for (int ky = 0; ky < 3; ++ky) {
#pragma unroll
      for (int kx = 0; kx < 3; ++kx) {
#pragma unroll
        for (int ks = 0; ks < 2; ++ks) {
          int cidx = c0 + ks * 16 + lq * 8;
          bf16x8 ah[2], al[2];
#pragma unroll
          for (int fm = 0; fm < 2; ++fm) {
            int widx = ((ky * 3 + kx) * 512 + fw + fm * 32 + li) * 512 + cidx;
            ah[fm] = as_b(*(const short8v*)(whi + widx));
            al[fm] = as_b(*(const short8v*)(wlo + widx));
          }
#pragma unroll
          for (int pn = 0; pn < 4; ++pn) {
            int srow = ((pxw + pn * 32) >> 6) + ky;
            int scol = (pn & 1) * 32 + li + kx;
            int loff = (srow * 66 + scol) * CPAD + ks * 16 + lq * 8;
            bf16x8 bh = as_b(*(const short8v*)(Xh + loff));
            bf16x8 bl = as_b(*(const short8v*)(Xl + loff));
            acc[0][pn] = __builtin_amdgcn_mfma_f32_32x32x16_bf16(ah[0], bh, acc[0][pn], 0, 0, 0);
            acc[1][pn] = __builtin_amdgcn_mfma_f32_32x32x16_bf16(ah[1], bh, acc[1][pn], 0, 0, 0);
            acc[0][pn] = __builtin_amdgcn_mfma_f32_32x32x16_bf16(ah[0], bl, acc[0][pn], 0, 0, 0);
            acc[1][pn] = __builtin_amdgcn_mfma_f32_32x32x16_bf16(ah[1], bl, acc[1][pn], 0, 0, 0);
            acc[0][pn] = __builtin_amdgcn_mfma_f32_32x32x16_bf16(al[0], bh, acc[0][pn], 0, 0, 0);
            acc[1][pn] = __builtin_amdgcn_mfma_f32_32x32x16_bf16(al[1], bh, acc[1][pn], 0, 0, 0);
          }
        }
      }
    }
  }

  // ---- epilogue: scale by d[n][f], store
  const float* dn = dco + n * 512;
  float* on = out + n * 512 * 64 * 64;
#pragma unroll
  for (int fm = 0; fm < 2; ++fm) {
#pragma unroll
    for (int pn = 0; pn < 4; ++pn) {
      int px = pxw + pn * 32 + li;
      int h = h0 + (px >> 6);
      int wcol = px & 63;
#pragma unroll
      for (int e = 0; e < 16; ++e) {
        int f = fw + fm * 32 + (e & 3) + 8 * (e >> 2) + 4 * lq;
        on[(f * 64 + h) * 64 + wcol] = acc[fm][pn][e] * dn[f];
      }
    }
  }
}

extern "C" void kernel_launch(void* const* d_in, const int* in_sizes, int n_in,
                              void* d_out, int out_size, void* d_ws, size_t ws_size,
                              hipStream_t stream) {
  const float* x  = (const float*)d_in[0];   // [8,512,64,64]
  const float* dl = (const float*)d_in[1];   // [8,512]
  const float* w  = (const float*)d_in[2];   // [3,3,512,512]
  const float* mw = (const float*)d_in[3];   // [512,512]
  const float* mb = (const float*)d_in[4];   // [512]
  float* out = (float*)d_out;

  char* wsb = (char*)d_ws;
  float* s_ws  = (float*)wsb;                         // 16 KB
  float* d_ws2 = (float*)(wsb + 16384);               // 16 KB
  float* wsq_w = (float*)(wsb + 32768);               // 1 MB
  u16*   whi   = (u16*)(wsb + 32768 + 1048576);       // 4.5 MB
  u16*   wlo   = whi + 9 * 512 * 512;                 // 4.5 MB

  style_k<<<16, 256, 0, stream>>>(dl, mw, mb, s_ws);
  wsq_k<<<1024, 256, 0, stream>>>(w, wsq_w);
  dcoef_k<<<16, 256, 0, stream>>>(s_ws, wsq_w, d_ws2);
  wsplit_k<<<576, 256, 0, stream>>>(w, whi, wlo);
  conv_k<<<512, 256, 0, stream>>>(x, s_ws, d_ws2, whi, wlo, out);
}